// Round 5
// baseline (2270.746 us; speedup 1.0000x reference)
//
#include <hip/hip_runtime.h>
#include <stdint.h>

// MoE top-2 layer: router -> grouped fc1(gelu,gate) -> grouped fc2 -> scatter-add.
// bf16 MFMA (16x16x32) with fp32 accumulation; fp32 weights converted in-flight.
// bf16 carried as raw u16 bits; RNE convert done bit-level (f2bf).

typedef unsigned short u16;
typedef __attribute__((ext_vector_type(4))) unsigned short u16x4;
typedef __attribute__((ext_vector_type(8))) __bf16 bf16x8;   // MFMA operand type (V8y)
typedef __attribute__((ext_vector_type(4))) float f32x4;

constexpr int T_TOK = 4096;
constexpr int HDIM  = 2048;
constexpr int FDIM  = 8192;
constexpr int NE    = 8;
constexpr int BM    = 128;
constexpr int MAXTILES = (2 * T_TOK) / BM + NE;   // 72 tile slots (static grid)
constexpr int MAXROWS  = 2 * T_TOK + NE * BM;     // 9216 padded assignment rows

#define AS1(p) ((__attribute__((address_space(1))) void*)(void*)(p))
#define AS3(p) ((__attribute__((address_space(3))) void*)(p))

__device__ __forceinline__ u16 f2bf(float f) {
  // round-to-nearest-even fp32 -> bf16 (finite inputs only)
  uint32_t u = __builtin_bit_cast(uint32_t, f);
  u += 0x7FFFu + ((u >> 16) & 1u);
  return (u16)(u >> 16);
}

__device__ __forceinline__ float gelu_tanh(float x) {
  // jax.nn.gelu approximate=True: 0.5x(1+tanh(sqrt(2/pi)(x+0.044715x^3)))
  float u = 0.7978845608028654f * (x + 0.044715f * x * x * x);
  float th = 1.f - 2.f / (1.f + __expf(2.f * u));   // tanh(u)
  return 0.5f * x * (1.f + th);
}

// ---------- cast hidden_states fp32 -> bf16 bits (vectorized, G13) ----------
__global__ void cast_x_kernel(const float* __restrict__ x, u16* __restrict__ xb) {
  size_t i = (size_t)blockIdx.x * blockDim.x + threadIdx.x;   // 8 elems per thread
  const float4* p = (const float4*)(x + i * 8);
  float4 a = p[0], b = p[1];
  uint4 o;
  o.x = (uint32_t)f2bf(a.x) | ((uint32_t)f2bf(a.y) << 16);
  o.y = (uint32_t)f2bf(a.z) | ((uint32_t)f2bf(a.w) << 16);
  o.z = (uint32_t)f2bf(b.x) | ((uint32_t)f2bf(b.y) << 16);
  o.w = (uint32_t)f2bf(b.z) | ((uint32_t)f2bf(b.w) << 16);
  *(uint4*)(xb + i * 8) = o;
}

// ---------- router: fp32 logits, top-2, softmax-over-2, scatter ----------
__global__ void router_kernel(const float* __restrict__ hs, const float* __restrict__ rw,
                              int* __restrict__ cnt, int* __restrict__ idx_list,
                              float* __restrict__ gate_list) {
  int t = blockIdx.x;
  int l = threadIdx.x;                 // one wave per token
  float acc[NE];
  #pragma unroll
  for (int e = 0; e < NE; ++e) acc[e] = 0.f;
  const float* row = hs + (size_t)t * HDIM;
  for (int h = l; h < HDIM; h += 64) {
    float x = row[h];
    const float* r8 = rw + (size_t)h * NE;
    #pragma unroll
    for (int e = 0; e < NE; ++e) acc[e] += x * r8[e];
  }
  #pragma unroll
  for (int off = 32; off > 0; off >>= 1) {
    #pragma unroll
    for (int e = 0; e < NE; ++e) acc[e] += __shfl_xor(acc[e], off);
  }
  if (l == 0) {
    int i0 = 0; float v0 = acc[0];
    #pragma unroll
    for (int e = 1; e < NE; ++e) if (acc[e] > v0) { v0 = acc[e]; i0 = e; }   // first-max = JAX tie rule
    int i1 = -1; float v1 = -1e30f;
    #pragma unroll
    for (int e = 0; e < NE; ++e) if (e != i0 && acc[e] > v1) { v1 = acc[e]; i1 = e; }
    float e1 = __expf(v1 - v0);        // <= 1, no overflow
    float inv = 1.f / (1.f + e1);
    int pos0 = atomicAdd(&cnt[i0], 1);
    idx_list[i0 * T_TOK + pos0] = t; gate_list[i0 * T_TOK + pos0] = inv;
    int pos1 = atomicAdd(&cnt[i1], 1);
    idx_list[i1 * T_TOK + pos1] = t; gate_list[i1 * T_TOK + pos1] = e1 * inv;
  }
}

// ---------- tile descriptors (serial, trivial) ----------
__global__ void build_tiles_kernel(const int* __restrict__ cnt, int* __restrict__ row_base,
                                   int* __restrict__ ntiles_arr, int* __restrict__ tile_e,
                                   int* __restrict__ tile_rb, int* __restrict__ n_tiles) {
  if (threadIdx.x == 0 && blockIdx.x == 0) {
    int rb = 0, nt = 0;
    for (int e = 0; e < NE; ++e) {
      row_base[e] = rb;
      int ntl = (cnt[e] + BM - 1) / BM;
      ntiles_arr[e] = ntl;
      for (int i = 0; i < ntl; ++i) { tile_e[nt] = e; tile_rb[nt] = rb + i * BM; ++nt; }
      rb += ntl * BM;
    }
    *n_tiles = nt;                     // <= 72
  }
}

// ---------- padded compaction: token_map/gate_map per global padded row ----------
__global__ void compact_kernel(const int* __restrict__ cnt, const int* __restrict__ row_base,
                               const int* __restrict__ ntiles_arr, const int* __restrict__ idx_list,
                               const float* __restrict__ gate_list, int* __restrict__ token_map,
                               float* __restrict__ gate_map) {
  int id = blockIdx.x * blockDim.x + threadIdx.x;
  int e = id / T_TOK, i = id % T_TOK;
  if (i < ntiles_arr[e] * BM) {
    int r = row_base[e] + i;
    if (i < cnt[e]) { token_map[r] = idx_list[e * T_TOK + i]; gate_map[r] = gate_list[e * T_TOK + i]; }
    else            { token_map[r] = 0; gate_map[r] = 0.f; }   // pad: gate 0 => h row = 0
  }
}

// ---------- grouped GEMM: 128x128 tile, BK=64, 4 waves, 16x16x32 bf16 MFMA ----------
// EPI=0: fc1  (A = gathered Xb rows, B = w1[e] [F][H], epilogue gelu*gate -> bf16 h)
// EPI=1: fc2  (A = h rows,           B = w2[e] [H][F], epilogue atomicAdd fp32 out)
// LDS layout: [128 rows][8 chunks of 16B], chunk XOR-swizzled by (row&7)  (T2; G21:
// A-side swizzle via pre-swizzled per-lane GLOBAL source of global_load_lds).
template <int EPI, int KDIM, int NDIM>
__global__ __launch_bounds__(256) void moe_gemm_kernel(
    const u16* __restrict__ Asrc, const float* __restrict__ Bsrc, void* __restrict__ Cdst,
    const int* __restrict__ tile_e, const int* __restrict__ tile_rb, const int* __restrict__ n_tiles,
    const int* __restrict__ token_map, const float* __restrict__ gate_map) {
  __shared__ __attribute__((aligned(128))) char smem_raw[32768];
  u16* As = (u16*)smem_raw;              // 128 x 64 bf16 = 16KB
  u16* Bs = (u16*)(smem_raw + 16384);    // 128 x 64 bf16 = 16KB

  int slot = blockIdx.y;
  if (slot >= *n_tiles) return;                // static grid, dynamic tile count
  int eid   = tile_e[slot];
  int rbase = tile_rb[slot];
  int nbase = blockIdx.x * 128;

  const float* Bexp = Bsrc + (size_t)eid * NDIM * KDIM + (size_t)nbase * KDIM;

  int tid = threadIdx.x;
  int l = tid & 63, w = tid >> 6;
  int wr = w >> 1, wc = w & 1;                 // 2x2 wave grid, 64x64 per wave

  // A staging: wave w stages rows w*32+j*8+(l>>3); source 16B-chunk pre-swizzled
  // (hardware writes lane l at wave-uniform base + l*16B = row (l>>3), slot (l&7))
  int schunk = (l & 7) ^ (l >> 3);
  const u16* srcA[4];
  #pragma unroll
  for (int j = 0; j < 4; ++j) {
    int r = rbase + w * 32 + j * 8 + (l >> 3);
    size_t arow = (EPI == 0) ? (size_t)token_map[r] * (size_t)KDIM : (size_t)r * (size_t)KDIM;
    srcA[j] = Asrc + arow + schunk * 8;
  }
  // B staging: thread covers float4-chunk bc4 of rows br0 + i*16 (coalesced 256B/16 lanes)
  int bc4 = tid & 15;
  int br0 = tid >> 4;
  // fragment read addressing
  int arow_l = wr * 64 + (l & 15);
  int brow_l = wc * 64 + (l & 15);
  int aswz = arow_l & 7;
  int bswz = brow_l & 7;
  int khi = l >> 4;

  f32x4 acc[4][4] = {};

  #pragma unroll 1
  for (int k0 = 0; k0 < KDIM; k0 += 64) {
    __syncthreads();                            // prev-iter reads done before overwrite
    #pragma unroll
    for (int j = 0; j < 4; ++j)
      __builtin_amdgcn_global_load_lds(AS1(srcA[j] + k0), AS3(As + (w * 32 + j * 8) * 64), 16, 0, 0);
    #pragma unroll
    for (int i = 0; i < 8; ++i) {
      int row = br0 + i * 16;
      float4 v = *(const float4*)(Bexp + (size_t)row * KDIM + k0 + bc4 * 4);
      u16x4 pk;
      pk[0] = f2bf(v.x); pk[1] = f2bf(v.y); pk[2] = f2bf(v.z); pk[3] = f2bf(v.w);
      int chunk = (bc4 >> 1) ^ (row & 7);
      *(u16x4*)(Bs + row * 64 + chunk * 8 + (bc4 & 1) * 4) = pk;
    }
    __syncthreads();                            // drains vmcnt (global_load_lds) + lgkm
    #pragma unroll
    for (int kks = 0; kks < 2; ++kks) {
      int kc = kks * 4 + khi;
      bf16x8 af[4], bfv[4];
      #pragma unroll
      for (int fr = 0; fr < 4; ++fr)
        af[fr] = *(const bf16x8*)(As + (arow_l + fr * 16) * 64 + ((kc ^ aswz) * 8));
      #pragma unroll
      for (int fc = 0; fc < 4; ++fc)
        bfv[fc] = *(const bf16x8*)(Bs + (brow_l + fc * 16) * 64 + ((kc ^ bswz) * 8));
      #pragma unroll
      for (int fr = 0; fr < 4; ++fr)
        #pragma unroll
        for (int fc = 0; fc < 4; ++fc)
          acc[fr][fc] = __builtin_amdgcn_mfma_f32_16x16x32_bf16(af[fr], bfv[fc], acc[fr][fc], 0, 0, 0);
    }
  }

  if (EPI == 0) {
    // gelu * gate, bounce through LDS (16B-chunk ^ (row&15) swizzle) for coalesced stores
    __syncthreads();
    u16* Cs = (u16*)smem_raw;            // 128 x 128 bf16 = 32KB (aliases As/Bs)
    #pragma unroll
    for (int fr = 0; fr < 4; ++fr) {
      #pragma unroll
      for (int fc = 0; fc < 4; ++fc) {
        int col = wc * 64 + fc * 16 + (l & 15);
        int cchunk = col >> 3, cin = col & 7;
        #pragma unroll
        for (int j = 0; j < 4; ++j) {
          int rowl = wr * 64 + fr * 16 + (l >> 4) * 4 + j;   // C/D: col=l&15, row=(l>>4)*4+j
          float g = gate_map[rbase + rowl];
          float x = acc[fr][fc][j];
          Cs[rowl * 128 + ((cchunk ^ (rowl & 15)) * 8) + cin] = f2bf(gelu_tanh(x) * g);
        }
      }
    }
    __syncthreads();
    u16* hdst = (u16*)Cdst;
    #pragma unroll
    for (int p = 0; p < 8; ++p) {
      int row = p * 16 + (tid >> 4);
      int chunk = tid & 15;
      uint4 v = *(const uint4*)(Cs + row * 128 + ((chunk ^ (row & 15)) * 8));
      *(uint4*)(hdst + (size_t)(rbase + row) * NDIM + nbase + chunk * 8) = v;
    }
  } else {
    // scatter-add into out; padded rows have h==0 -> add 0 to token 0 (harmless)
    float* od = (float*)Cdst;
    #pragma unroll
    for (int fr = 0; fr < 4; ++fr) {
      #pragma unroll
      for (int fc = 0; fc < 4; ++fc) {
        int col = nbase + wc * 64 + fc * 16 + (l & 15);
        #pragma unroll
        for (int j = 0; j < 4; ++j) {
          int rowl = wr * 64 + fr * 16 + (l >> 4) * 4 + j;
          int tok = token_map[rbase + rowl];
          atomicAdd(od + (size_t)tok * NDIM + col, acc[fr][fc][j]);
        }
      }
    }
  }
}

extern "C" void kernel_launch(void* const* d_in, const int* in_sizes, int n_in,
                              void* d_out, int out_size, void* d_ws, size_t ws_size,
                              hipStream_t stream) {
  const float* hs = (const float*)d_in[0];
  const float* rw = (const float*)d_in[1];
  const float* w1 = (const float*)d_in[2];
  const float* w2 = (const float*)d_in[3];
  float* out = (float*)d_out;

  // workspace layout (~168 MB):
  char* ws = (char*)d_ws;
  constexpr size_t XB_BYTES = (size_t)T_TOK * HDIM * 2;          // 16 MiB bf16 X
  constexpr size_t HB_BYTES = (size_t)MAXROWS * FDIM * 2;        // 151 MiB bf16 h
  u16* Xb   = (u16*)ws;
  u16* hbuf = (u16*)(ws + XB_BYTES);
  int* meta = (int*)(ws + XB_BYTES + HB_BYTES);
  int*   cnt        = meta;                 // 8
  int*   row_base   = meta + 8;             // 8
  int*   ntiles_arr = meta + 16;            // 8
  int*   tile_e     = meta + 24;            // 80
  int*   tile_rb    = meta + 104;           // 80
  int*   n_tiles    = meta + 184;           // 1 (+7 pad)
  int*   idx_list   = meta + 192;           // E*T
  float* gate_list  = (float*)(meta + 192 + NE * T_TOK);
  int*   token_map  = meta + 192 + 2 * NE * T_TOK;
  float* gate_map   = (float*)(meta + 192 + 2 * NE * T_TOK + MAXROWS);

  hipMemsetAsync(cnt, 0, NE * sizeof(int), stream);
  hipMemsetAsync(out, 0, (size_t)out_size * sizeof(float), stream);

  cast_x_kernel<<<(T_TOK * HDIM / 8) / 256, 256, 0, stream>>>(hs, Xb);
  router_kernel<<<T_TOK, 64, 0, stream>>>(hs, rw, cnt, idx_list, gate_list);
  build_tiles_kernel<<<1, 64, 0, stream>>>(cnt, row_base, ntiles_arr, tile_e, tile_rb, n_tiles);
  compact_kernel<<<(NE * T_TOK) / 256, 256, 0, stream>>>(cnt, row_base, ntiles_arr,
                                                         idx_list, gate_list, token_map, gate_map);
  // fc1: h = gelu(X @ w1[e]^T) * gate   [K=2048, N=8192]
  moe_gemm_kernel<0, HDIM, FDIM><<<dim3(FDIM / 128, MAXTILES), 256, 0, stream>>>(
      Xb, w1, (void*)hbuf, tile_e, tile_rb, n_tiles, token_map, gate_map);
  // fc2: out += h @ w2[e]^T             [K=8192, N=2048]
  moe_gemm_kernel<1, FDIM, HDIM><<<dim3(HDIM / 128, MAXTILES), 256, 0, stream>>>(
      hbuf, w2, (void*)out, tile_e, tile_rb, n_tiles, token_map, gate_map);
}